// Round 16
// baseline (210.225 us; speedup 1.0000x reference)
//
#include <hip/hip_runtime.h>
#include <hip/hip_bf16.h>
#include <math.h>
#include <stdint.h>

// Problem constants (reference: B=4, T=2048, C=1024, H=16, HD=64)
#define BB 4
#define TT 2048
#define CC 1024
#define HH 16
#define HD 64
#define MM (BB*TT)   // 8192
#define NQT2 16      // T / 128 q-tiles for attention (QBLK=128)
#define SCQ 0.180336878f   // (1/sqrt(HD)) * log2(e): Q pre-scale for exp2-domain softmax

using f32x2  = __attribute__((ext_vector_type(2))) float;
using f32x4  = __attribute__((ext_vector_type(4))) float;
using f32x16 = __attribute__((ext_vector_type(16))) float;
using i32x4  = __attribute__((ext_vector_type(4))) int;
using bf16x4 = __attribute__((ext_vector_type(4))) __bf16;
using bf16x8 = __attribute__((ext_vector_type(8))) __bf16;

__device__ __forceinline__ float fast_exp2(float x) {
  return __builtin_amdgcn_exp2f(x);   // v_exp_f32 (native exp2 on gfx950)
}

__device__ __forceinline__ int cvt_pk_bf16(float lo, float hi_) {
  int r;
  asm("v_cvt_pk_bf16_f32 %0, %1, %2" : "=v"(r) : "v"(lo), "v"(hi_));
  return r;   // low 16 = bf16(lo), high 16 = bf16(hi_)
}

__device__ __forceinline__ f32x2 max2(f32x2 a, f32x2 b) {
  return __builtin_elementwise_max(a, b);   // v_pk_max_f32
}

__device__ __forceinline__ void gload_lds16(const void* g, void* l) {
  __builtin_amdgcn_global_load_lds(
      (__attribute__((address_space(1))) void*)(void*)(g),
      (__attribute__((address_space(3))) void*)(l), 16, 0, 0);
}

// ---------------- fp32 -> bf16 converts ----------------
__global__ __launch_bounds__(256)
void cvt_f32_bf16(const float* __restrict__ s, __bf16* __restrict__ d, int n4) {
  int i = blockIdx.x * 256 + threadIdx.x;
  if (i >= n4) return;
  float4 v = ((const float4*)s)[i];
  bf16x4 o;
  o[0] = (__bf16)v.x; o[1] = (__bf16)v.y; o[2] = (__bf16)v.z; o[3] = (__bf16)v.w;
  *(bf16x4*)(d + (size_t)i * 4) = o;
}

// 4 weights in one launch; Wq scaled by SCQ and Wq/Wk/Wv written into the
// contiguous [3072][1024] concat buffer (order q,k,v); Wp separate.
__global__ __launch_bounds__(256)
void cvt_w4(const float* __restrict__ Wq, const float* __restrict__ Wk,
            const float* __restrict__ Wv, const float* __restrict__ Wp,
            __bf16* __restrict__ wqkv, __bf16* __restrict__ wpb) {
  int which = blockIdx.y;
  const float* s = which == 0 ? Wq : which == 1 ? Wk : which == 2 ? Wv : Wp;
  __bf16* d = which == 3 ? wpb : wqkv + (size_t)which * CC * CC;
  float sc = which == 0 ? SCQ : 1.f;
  int i = blockIdx.x * 256 + threadIdx.x;   // grid.x = (CC*CC/4)/256 = 1024
  float4 v = ((const float4*)s)[i];
  bf16x4 o;
  o[0] = (__bf16)(v.x * sc); o[1] = (__bf16)(v.y * sc);
  o[2] = (__bf16)(v.z * sc); o[3] = (__bf16)(v.w * sc);
  *(bf16x4*)(d + (size_t)i * 4) = o;
}

#define WAITV4 asm volatile("s_waitcnt vmcnt(4)" ::: "memory")
#define WAITV2 asm volatile("s_waitcnt vmcnt(2)" ::: "memory")
#define WAITV0 asm volatile("s_waitcnt vmcnt(0)" ::: "memory")
#define BARR   __builtin_amdgcn_s_barrier()
#define SB0    __builtin_amdgcn_sched_barrier(0)

// ==== QKV GEMM v14: B-operand DIRECT FROM GLOBAL (LDS-volume halving) =======
// C[8192,3072] = A[8192,1024] x Wqkv[3072,1024]^T + bias.
// LDS-BW accounting (r15 post-mortem): per block-iter the r13 structure moved
// 48KB through the LDS pipe (A+B each read by 2 waves + 16KB staged) vs a
// 20.6us MFMA floor -> ~40us serial LDS time explains MfmaUtil pinned at 26%
// across all seven prior structures. v14 removes B from LDS entirely:
// B (weights, 6MB, L2-resident) is loaded per-lane global->VGPR with the
// natural chunk-g content the slot-swizzle round-trip delivered. LDS traffic
// 48 -> 24 KB per block-iter; LDS 24.6KB (3x A bufs; lt alias).
// FIFO ledger per iter: [WAITV2 (A(t)+B(t) done; A(t+1) in flight); BARR;
// issue B(t+1)->bvn; SB0; issue A-stage(t+2); compute with bvc; bvc=bvn
// (compiler wait here = equivalent sync point)]. Prologue [A0, B0, A1].
// proj 0/1 (Q,K): bf16 head-split store; proj 2 (V): 2x 64-col LDS transpose
// chunks -> Vt[bh][d][t].
__global__ __launch_bounds__(256, 2)
void gemm_qkv(const __bf16* __restrict__ A, const __bf16* __restrict__ Bm,
              const float* __restrict__ b0, const float* __restrict__ b1,
              const float* __restrict__ b2, __bf16* __restrict__ out,
              __bf16* __restrict__ vt) {
  __shared__ __bf16 U[12288];        // 24KB: A bufs 0..2 @ b*8192B; lt alias
  char* Ub = (char*)U;
  const int tid = threadIdx.x;
  const int wid = tid >> 6, lane = tid & 63;
  const int g = lane >> 4, lq = lane & 15;
  // XCD-chunk swizzle: 1536 blocks = 8 XCDs x 192 contiguous logicals
  const int bx0 = blockIdx.x;
  const int bx = (bx0 & 7) * 192 + (bx0 >> 3);
  const int bm = bx / 24, bn = bx % 24;
  const int brow = bm << 7, bcol = bn << 7;
  const int wr = (wid >> 1) << 6, wc = (wid & 1) << 6;

  // A staging: thread handles chunks c0=tid, c1=tid+256 (16B each).
  // chunk c -> LDS row c>>2, slot c&3 (linear dest); global source column is
  // inverse-swizzled so read-side slot=(g+(row>>1))&3 recovers K-chunk g.
  const int c0 = tid, c1 = tid + 256;
  const int r0 = c0 >> 2, s0_ = (((c0 & 3) - (r0 >> 1)) & 3) << 4;
  const int r1 = c1 >> 2, s1_ = (((c1 & 3) - (r1 >> 1)) & 3) << 4;
  const char* Ag = (const char*)A;
  // B direct-load base: this lane reads rows (bcol + wc + n*16 + lq), chunk g
  const char* Bg = (const char*)Bm + (size_t)(bcol + wc + lq) * 2048 + g * 16;

#define STAGEA(ko, buf)                                                       \
  {                                                                           \
    gload_lds16(Ag + (size_t)(brow + r0) * 2048 + (ko) + s0_,                 \
                Ub + (buf) * 8192 + c0 * 16);                                 \
    gload_lds16(Ag + (size_t)(brow + r1) * 2048 + (ko) + s1_,                 \
                Ub + (buf) * 8192 + c1 * 16);                                 \
  }

  f32x4 acc[4][4] = {};
  bf16x8 bvc[4], bvn[4];

  // prologue, FIFO order [A(0) 2ops, B(0) 4ops, A(1) 2ops]
  STAGEA(0, 0);
  SB0;
#pragma unroll
  for (int n = 0; n < 4; ++n)
    bvc[n] = *(const bf16x8*)(Bg + (size_t)n * 16 * 2048);
  SB0;
  STAGEA(64, 1);
  int cur = 0;
#pragma unroll 1
  for (int t = 0; t < 32; ++t) {
    if (t + 1 < 32) { WAITV2; } else { WAITV0; }  // A(t)+B(t) landed
    BARR; SB0;                       // A(t) visible; buf[(t+2)%3] free
    if (t + 1 < 32) {                // B(t+1) -> bvn (issued BEFORE A-stage)
      const size_t ktb = (size_t)(t + 1) << 6;
#pragma unroll
      for (int n = 0; n < 4; ++n)
        bvn[n] = *(const bf16x8*)(Bg + (size_t)n * 16 * 2048 + ktb);
      SB0;                           // pin B-load group before A-stage group
    }
    if (t + 2 < 32) {
      int nb = cur + 2; if (nb >= 3) nb -= 3;
      STAGEA((t + 2) << 6, nb);
    }
    const char* Ac = Ub + cur * 8192;
    bf16x8 av[4];
#pragma unroll
    for (int m = 0; m < 4; ++m) {
      int row = wr + m * 16 + lq;
      int sl = (g + (row >> 1)) & 3;
      av[m] = *(const bf16x8*)(Ac + row * 64 + sl * 16);
    }
#pragma unroll
    for (int m = 0; m < 4; ++m)
#pragma unroll
      for (int n = 0; n < 4; ++n)
        acc[m][n] = __builtin_amdgcn_mfma_f32_16x16x32_bf16(av[m], bvc[n], acc[m][n], 0, 0, 0);
    SB0;
    if (t + 1 < 32) {
#pragma unroll
      for (int n = 0; n < 4; ++n) bvc[n] = bvn[n];   // compiler wait lands here
    }
    cur = (cur == 2) ? 0 : cur + 1;
  }
#undef STAGEA

  const int proj = bn >> 3;   // uniform per block (8 x 128 = 1024 cols / proj)
  if (proj < 2) {
    // epilogue: bias + bf16 head-split store [proj][B,H,T,HD]
    const float* bias = proj == 0 ? b0 : b1;
    const float bsc = proj == 0 ? SCQ : 1.f;
#pragma unroll
    for (int n = 0; n < 4; ++n) {
      int col = bcol + wc + n * 16 + lq;
      int cw = col & (CC - 1);
      float bb = bias[cw] * bsc;
      int h_ = cw >> 6, d_ = cw & (HD - 1);
#pragma unroll
      for (int m = 0; m < 4; ++m) {
        int row0 = brow + wr + m * 16 + g * 4;
#pragma unroll
        for (int i = 0; i < 4; ++i) {
          int row = row0 + i;
          int b_ = row >> 11, t_ = row & (TT - 1);
          out[((size_t)proj << 23) +
              ((((size_t)b_ * HH + h_) * TT + t_) << 6) + d_] =
              (__bf16)(acc[m][n][i] + bb);
        }
      }
    }
  } else {
    // V: transpose 128x128 tile through lt (2 chunks of 64 cols = 1 head
    // each) -> Vt[bh][d][t] coalesced. lt ALIASES A buffers: barrier first.
    __syncthreads();                             // all K-loop LDS reads done
    __bf16* lt = U;                              // [64 cols][130 rows]
    const int cv0 = (bn & 7) << 7;               // col offset within V region
    const int b_ = brow >> 11, t0 = brow & (TT - 1);
    const int hbase = (bn & 7) << 1;
    const int rd_d = tid >> 2, rd_tb = (tid & 3) << 5;   // 64 d x 128 t
#pragma unroll
    for (int cc = 0; cc < 2; ++cc) {
      if ((wid & 1) == cc) {                     // 2 writer waves per chunk
#pragma unroll
        for (int n = 0; n < 4; ++n) {
          int c = (n << 4) + lq;                 // 0..63 within chunk
          float bb = b2[cv0 + (cc << 6) + c];
#pragma unroll
          for (int m = 0; m < 4; ++m) {
            int r = wr + (m << 4) + (g << 2);    // 0..127 over both writers
            bf16x4 pk;
#pragma unroll
            for (int i = 0; i < 4; ++i)
              pk[i] = (__bf16)(acc[m][n][i] + bb);
            *(bf16x4*)(lt + c * 130 + r) = pk;
          }
        }
      }
      __syncthreads();
      // readers: all 256 threads; d = tid>>2, 32 t-elems each
      __bf16* dst = vt + (((size_t)((b_ * HH + hbase + cc) * HD + rd_d)) << 11)
                       + t0 + rd_tb;
      const __bf16* srcl = lt + rd_d * 130 + rd_tb;
#pragma unroll
      for (int j = 0; j < 4; ++j)
        *(bf16x8*)(dst + j * 8) = *(const bf16x8*)(srcl + j * 8);
      __syncthreads();
    }
  }
}

// ==== proj GEMM v13 (unchanged control): triple-buffered pipeline ===========
__global__ __launch_bounds__(256, 2)
void gemm_proj(const __bf16* __restrict__ A, const __bf16* __restrict__ Bm,
               const float* __restrict__ bias, float* __restrict__ out) {
  __shared__ __bf16 U[24576];        // 48KB: A bufs @ b*8192, B @ 24576+b*8192
  char* Ub = (char*)U;
  const int tid = threadIdx.x;
  const int wid = tid >> 6, lane = tid & 63;
  const int g = lane >> 4, lq = lane & 15;
  // XCD-chunk swizzle: 512 blocks = 8 XCDs x 64 contiguous logicals
  const int bx0 = blockIdx.x;
  const int bx = (bx0 & 7) * 64 + (bx0 >> 3);
  const int brow = (bx >> 3) << 7;         // 64 bm
  const int bcol = (bx & 7) << 7;          // 8 bn
  const int wr = (wid >> 1) << 6, wc = (wid & 1) << 6;

  const int c0 = tid, c1 = tid + 256;
  const int r0 = c0 >> 2, s0_ = (((c0 & 3) - (r0 >> 1)) & 3) << 4;
  const int r1 = c1 >> 2, s1_ = (((c1 & 3) - (r1 >> 1)) & 3) << 4;
  const char* Ag = (const char*)A;
  const char* Bg = (const char*)Bm;

#define STAGEP(ko, buf)                                                       \
  {                                                                           \
    gload_lds16(Ag + (size_t)(brow + r0) * 2048 + (ko) + s0_,                 \
                Ub + (buf) * 8192 + c0 * 16);                                 \
    gload_lds16(Ag + (size_t)(brow + r1) * 2048 + (ko) + s1_,                 \
                Ub + (buf) * 8192 + c1 * 16);                                 \
    gload_lds16(Bg + (size_t)(bcol + r0) * 2048 + (ko) + s0_,                 \
                Ub + 24576 + (buf) * 8192 + c0 * 16);                         \
    gload_lds16(Bg + (size_t)(bcol + r1) * 2048 + (ko) + s1_,                 \
                Ub + 24576 + (buf) * 8192 + c1 * 16);                         \
  }

  f32x4 acc[4][4] = {};

  STAGEP(0, 0); STAGEP(64, 1);
  int cur = 0;
#pragma unroll 1
  for (int t = 0; t < 32; ++t) {
    if (t + 1 < 32) { WAITV4; } else { WAITV0; }
    BARR; SB0;
    if (t + 2 < 32) {
      int nb = cur + 2; if (nb >= 3) nb -= 3;
      STAGEP((t + 2) << 6, nb);
    }
    const char* Ac = Ub + cur * 8192;
    const char* Bc = Ub + 24576 + cur * 8192;
    bf16x8 av[4], bv[4];
#pragma unroll
    for (int m = 0; m < 4; ++m) {
      int row = wr + m * 16 + lq;
      int sl = (g + (row >> 1)) & 3;
      av[m] = *(const bf16x8*)(Ac + row * 64 + sl * 16);
    }
#pragma unroll
    for (int n = 0; n < 4; ++n) {
      int row = wc + n * 16 + lq;
      int sl = (g + (row >> 1)) & 3;
      bv[n] = *(const bf16x8*)(Bc + row * 64 + sl * 16);
    }
#pragma unroll
    for (int m = 0; m < 4; ++m)
#pragma unroll
      for (int n = 0; n < 4; ++n)
        acc[m][n] = __builtin_amdgcn_mfma_f32_16x16x32_bf16(av[m], bv[n], acc[m][n], 0, 0, 0);
    SB0;
    cur = (cur == 2) ? 0 : cur + 1;
  }
#undef STAGEP

#pragma unroll
  for (int m = 0; m < 4; ++m) {
#pragma unroll
    for (int n = 0; n < 4; ++n) {
      int col = bcol + wc + n * 16 + lq;
      float bb = bias[col];
      int row0 = brow + wr + m * 16 + g * 4;
#pragma unroll
      for (int i = 0; i < 4; ++i)
        out[(size_t)(row0 + i) * CC + col] = acc[m][n][i] + bb;
    }
  }
}

// ---------------- Flash attention v6 (unchanged control) --------------------
// grid 1024 = 16 q-tiles x 64 bh, 256 threads = 4 waves x 32 q-rows (QBLK=128).
// 32x32x16 MFMA, swapped QK^T, split-half S, in-register softmax.
// Full-grid residency: double-buffered K/V (32.8KB LDS) + launch_bounds(256,4)
// -> 4 blocks/CU -> all 1024 blocks co-resident. Heavy-first Latin-square qi
// map balances per-CU work. One barrier per tile, counted staging.
// C/D layout (m74/m101): col = lane&31, row = (r&3) + 8*(r>>2) + 4*(lane>>5).
__global__ __launch_bounds__(256, 4)
void attn_fwd(const __bf16* __restrict__ Q, const __bf16* __restrict__ K,
              const __bf16* __restrict__ Vt, const int* __restrict__ pm,
              __bf16* __restrict__ Y) {
  __shared__ __bf16 Ks[2][64 * 64];   // 16 KiB
  __shared__ __bf16 Vs[2][64 * 64];   // 16 KiB
  __shared__ int flg;
  const int tid = threadIdx.x, wid = tid >> 6, lane = tid & 63;
  const int l31 = lane & 31, hi = lane >> 5;
  const int bx = blockIdx.x;
  const int bh = bx & 63, jj = bx >> 6;          // jj 0..15
  const int qi = 15 - (4 * (jj >> 2) + ((jj + (jj >> 2)) & 3));
  const int b_ = bh >> 4, h_ = bh & 15;
  const __bf16* Qb = Q + (size_t)bh * TT * HD;
  const __bf16* Kb = K + (size_t)bh * TT * HD;
  const __bf16* Vb = Vt + (size_t)bh * HD * TT;
  const int* pmb = pm + b_ * TT;

  const int so = tid * 16;                 // 16B chunk, 0..4080
  const int srow = tid >> 3;               // 0..31
  const int scol = (so & 127) ^ ((srow & 7) << 4);   // inverse-swizzled src col

  const int q0 = qi << 7;
  const int qw = q0 + wid * 32;            // this wave's 32 q-rows
  const int ntiles = 2 * qi + 2;           // >= 2 always
  const int sw0 = (l31 & 7) << 4;

  // Q fragments: lane holds Q[qw+l31][16s + 8hi .. +7], s=0..3
  bf16x8 qf[4];
#pragma unroll
  for (int s = 0; s < 4; ++s)
    qf[s] = *(const bf16x8*)(Qb + (size_t)(qw + l31) * HD + s * 16 + hi * 8);
  SB0;   // pin qf loads above the staging issues (vmcnt accounting)

  // padding-mask block check: 256 threads x 2 int4 cover the 2048-int pm row
  int4 pa4 = ((const int4*)pmb)[tid];
  int4 pb4 = ((const int4*)pmb)[tid + 256];
  bool okp = pa4.x && pa4.y && pa4.z && pa4.w &&
             pb4.x && pb4.y && pb4.z && pb4.w;
  if (tid == 0) flg = 1;
  __syncthreads();
  if (!okp) flg = 0;                       // benign race (all writers store 0)

  // prologue: stage tile 0 into buf 0 (4 gloads: 2 K + 2 V)
  {
    char* kd = (char*)&Ks[0][0] + so;
    char* vd = (char*)&Vs[0][0] + so;
#pragma unroll
    for (int j = 0; j < 2; ++j) {
      gload_lds16((const char*)Kb + (size_t)(srow + 32 * j) * 128 + scol,
                  kd + j * 4096);
      gload_lds16((const char*)Vb + (size_t)(srow + 32 * j) * (TT * 2) + scol,
                  vd + j * 4096);
    }
  }
  __syncthreads();                         // tile 0 staged everywhere; flg final
  const bool allones = (flg != 0);

  f32x16 o0 = {}, o1 = {};                 // O[q=crow(r,hi)][d = l31 | 32+l31]
  f32x16 vzero = {};                       // persistent zero C-operand
  float lsum = 0.f;                        // partial row-sum (this lane-half)
  float m = -INFINITY;                     // running max for q = qw+l31

  int cur = 0;
#pragma unroll 1
  for (int t = 0; t < ntiles; ++t) {
    const int kv0 = t << 6;
    // ---- own stage(t) done (issued a full compute phase ago -> cheap) ----
    WAITV0;
    __builtin_amdgcn_s_barrier(); SB0;  // tile t staged AND t-1 reads done
    // ---- issue stage(t+1) into buf[cur^1] (tile t-1's slot, now free) ----
    if (t + 1 < ntiles) {
      char* kd = (char*)&Ks[0][0] + (cur ^ 1) * 8192 + so;
      char* vd = (char*)&Vs[0][0] + (cur ^ 1) * 8192 + so;
      const size_t nk = (size_t)(kv0 + 64);
#pragma unroll
      for (int j = 0; j < 2; ++j) {
        gload_lds16((const char*)Kb + (nk + srow + 32 * j) * 128 + scol,
                    kd + j * 4096);
        gload_lds16((const char*)Vb + (size_t)(srow + 32 * j) * (TT * 2) +
                        nk * 2 + scol,
                    vd + j * 4096);
      }
    }

    unsigned long long bits = ~0ull;
    if (__builtin_expect(!allones, 0))     // rare slow path
      bits = __ballot(pmb[kv0 + lane] != 0);

    if (kv0 <= qw + 31) {                  // wave-uniform participation
      const char* VsC = (const char*)&Vs[0][0] + cur * 8192;

#pragma unroll
      for (int h = 0; h < 2; ++h) {
        const int kvh = kv0 + 32 * h;
        if (kvh <= qw + 31) {              // wave-uniform per-half gate
          // ---- QK^T (swapped): S[kvh+crow][q=l31] ----
          const char* KsC =
              (const char*)&Ks[0][0] + cur * 8192 + (32 * h + l31) * 128;
          f32x16 S;
          __builtin_amdgcn_s_setprio(1);
          {
            bf16x8 k0 = *(const bf16x8*)(KsC + ((16 * hi) ^ sw0));
            S = __builtin_amdgcn_mfma_f32_32x32x16_bf16(k0, qf[0], vzero, 0, 0, 0);
          }
#pragma unroll
          for (int s = 1; s < 4; ++s) {
            bf16x8 kf = *(const bf16x8*)(KsC + ((32 * s + 16 * hi) ^ sw0));
            S = __builtin_amdgcn_mfma_f32_32x32x16_bf16(kf, qf[s], S, 0, 0, 0);
          }
          __builtin_amdgcn_s_setprio(0);

          // ---- masks ----
          if (__builtin_expect(bits != ~0ull, 0)) {   // padding (rare)
#pragma unroll
            for (int r = 0; r < 16; ++r) {
              const int c = (r & 3) + 8 * (r >> 2);
              if (!((bits >> (32 * h + c + 4 * hi)) & 1ull)) S[r] = -INFINITY;
            }
          }
          if (kvh + 31 > qw) {             // causal diag (wave-uniform)
            const int thr = qw + l31 - kvh - 4 * hi;
#pragma unroll
            for (int r = 0; r < 16; ++r) {
              const int c = (r & 3) + 8 * (r >> 2);
              S[r] = (c <= thr) ? S[r] : -INFINITY;
            }
          }

          // ---- row max via packed-f32 tree + defer-rescale check ----
          f32x2 x0 = {S[0], S[1]},  x1 = {S[2], S[3]};
          f32x2 x2 = {S[4], S[5]},  x3 = {S[6], S[7]};
          f32x2 x4 = {S[8], S[9]},  x5 = {S[10], S[11]};
          f32x2 x6 = {S[12], S[13]}, x7 = {S[14], S[15]};
          x0 = max2(x0, x4); x1 = max2(x1, x5);
          x2 = max2(x2, x6); x3 = max2(x3, x7);
          x0 = max2(x0, x2); x1 = max2(x1, x3);
          x0 = max2(x0, x1);
          float pmax = fmaxf(x0[0], x0[1]);
          if (!__all(pmax <= m + 8.f)) {
            float nm = fmaxf(pmax, __shfl_xor(pmax, 32));  // full row max
            float mn = fmaxf(m, nm);
            float c = fast_exp2(m - mn);
            m = mn;
            lsum *= c;
#pragma unroll
            for (int r = 0; r < 16; ++r) {
              float cr = __shfl(c, (r & 3) + 8 * (r >> 2) + 4 * hi);
              o0[r] *= cr;
              o1[r] *= cr;
            }
          }

          // ---- P = exp2(S - m) (packed sub, trans exp) ----
          const f32x2 mm = {m, m};
#pragma unroll
          for (int r = 0; r < 16; r += 2) {
            f32x2 u = {S[r], S[r + 1]};
            u -= mm;                      // v_pk_add_f32
            S[r] = fast_exp2(u[0]);
            S[r + 1] = fast_exp2(u[1]);
          }
          // ---- in-lane row-sum via packed-f32 tree ----
          {
            f32x2 u0 = {S[0], S[1]},  u1 = {S[2], S[3]};
            f32x2 u2 = {S[4], S[5]},  u3 = {S[6], S[7]};
            f32x2 u4 = {S[8], S[9]},  u5 = {S[10], S[11]};
            f32x2 u6 = {S[12], S[13]}, u7 = {S[14], S[15]};
            u0 += u4; u1 += u5; u2 += u6; u3 += u7;
            u0 += u2; u1 += u3;
            u0 += u1;
            lsum += u0[0] + u0[1];
          }

          // ---- PV: build A-fragments (validated select+shfl_xor exchange) ----
          __builtin_amdgcn_s_setprio(1);
#pragma unroll
          for (int s = 0; s < 2; ++s) {
            int A0 = cvt_pk_bf16(S[8 * s + 0], S[8 * s + 1]);
            int A1 = cvt_pk_bf16(S[8 * s + 2], S[8 * s + 3]);
            int B0 = cvt_pk_bf16(S[8 * s + 4], S[8 * s + 5]);
            int B1 = cvt_pk_bf16(S[8 * s + 6], S[8 * s + 7]);
            // exchange across lane+-32: lo lanes need A-pairs of BOTH halves,
            // hi lanes need B-pairs of BOTH halves.
            int s0 = hi ? A0 : B0, s1 = hi ? A1 : B1;
            int e0 = __shfl_xor(s0, 32), e1 = __shfl_xor(s1, 32);
            i32x4 wv;
            wv[0] = hi ? e0 : A0;
            wv[1] = hi ? e1 : A1;
            wv[2] = hi ? B0 : e0;
            wv[3] = hi ? B1 : e1;
            bf16x8 pa = __builtin_bit_cast(bf16x8, wv);
            const int co = 64 * h + 32 * s + 16 * hi;   // kv byte offset
            bf16x8 v0 = *(const bf16x8*)(VsC + l31 * 128 + (co ^ sw0));
            bf16x8 v1 = *(const bf16x8*)(VsC + (32 + l31) * 128 + (co ^ sw0));
            o0 = __builtin_amdgcn_mfma_f32_32x32x16_bf16(pa, v0, o0, 0, 0, 0);
            o1 = __builtin_amdgcn_mfma_f32_32x32x16_bf16(pa, v1, o1, 0, 0, 0);
          }
          __builtin_amdgcn_s_setprio(0);
        }
      }
    }
    SB0;   // pin this tile's LDS reads above next iteration's barrier
    cur ^= 1;
  }

  // epilogue: combine lane-halves' row-sums, normalize + store
  float linv = 1.f / (lsum + __shfl_xor(lsum, 32));
#pragma unroll
  for (int r = 0; r < 16; ++r) {
    const int crow = (r & 3) + 8 * (r >> 2) + 4 * hi;
    float ir = __shfl(linv, crow);
    const int qrow = qw + crow;
    __bf16* yp = Y + ((size_t)(b_ * TT + qrow)) * CC + h_ * HD + l31;
    yp[0]  = (__bf16)(o0[r] * ir);
    yp[32] = (__bf16)(o1[r] * ir);
  }
}

// ---------------- launch ----------------
extern "C" void kernel_launch(void* const* d_in, const int* in_sizes, int n_in,
                              void* d_out, int out_size, void* d_ws, size_t ws_size,
                              hipStream_t stream) {
  (void)in_sizes; (void)n_in; (void)out_size; (void)ws_size;
  const float* x  = (const float*)d_in[0];
  const float* Wk = (const float*)d_in[1];
  const float* bk = (const float*)d_in[2];
  const float* Wq = (const float*)d_in[3];
  const float* bq = (const float*)d_in[4];
  const float* Wv = (const float*)d_in[5];
  const float* bv = (const float*)d_in[6];
  const float* Wp = (const float*)d_in[7];
  const float* bp = (const float*)d_in[8];
  const int* pmask = (const int*)d_in[9];

  char* ws = (char*)d_ws;
  const size_t MB = 1024 * 1024;
  __bf16* xb   = (__bf16*)(ws);            // 16MB; reused as attn-out y
  __bf16* wqkv = (__bf16*)(ws + 16 * MB);  // 6MB  [3072][1024] (q,k,v concat)
  __bf16* wpb  = (__bf16*)(ws + 22 * MB);  // 2MB
  __bf16* qb   = (__bf16*)(ws + 24 * MB);  // 16MB [B,H,T,HD]
  __bf16* kb   = qb + ((size_t)1 << 23);   // 16MB @40MB
  __bf16* vtb  = (__bf16*)(ws + 56 * MB);  // 16MB [B,H,HD,T] (written by gemm_qkv)
  __bf16* yb   = xb;                       // attn out overwrites x

  int n4 = (MM * CC) / 4;                  // 2097152
  cvt_f32_bf16<<<(n4 + 255) / 256, 256, 0, stream>>>(x, xb, n4);
  cvt_w4<<<dim3((CC * CC / 4) / 256, 4), 256, 0, stream>>>(
      Wq, Wk, Wv, Wp, wqkv, wpb);

  // fused QKV projection + V-transpose epilogue (128x128 tiles, grid 1536)
  gemm_qkv<<<(MM / 128) * (3 * CC / 128), 256, 0, stream>>>(
      xb, wqkv, bq, bk, bv, qb, vtb);

  attn_fwd<<<NQT2 * BB * HH, 256, 0, stream>>>(qb, kb, vtb, pmask, yb);

  gemm_proj<<<(MM / 128) * (CC / 128), 256, 0, stream>>>(
      yb, wpb, bp, (float*)d_out);
}

// Round 17
// 168.996 us; speedup vs baseline: 1.2440x; 1.2440x over previous
//
#include <hip/hip_runtime.h>
#include <hip/hip_bf16.h>
#include <math.h>
#include <stdint.h>

// Problem constants (reference: B=4, T=2048, C=1024, H=16, HD=64)
#define BB 4
#define TT 2048
#define CC 1024
#define HH 16
#define HD 64
#define MM (BB*TT)   // 8192
#define NQT2 16      // T / 128 q-tiles for attention (QBLK=128)
#define SCQ 0.180336878f   // (1/sqrt(HD)) * log2(e): Q pre-scale for exp2-domain softmax

using f32x2  = __attribute__((ext_vector_type(2))) float;
using f32x4  = __attribute__((ext_vector_type(4))) float;
using f32x16 = __attribute__((ext_vector_type(16))) float;
using i32x4  = __attribute__((ext_vector_type(4))) int;
using bf16x4 = __attribute__((ext_vector_type(4))) __bf16;
using bf16x8 = __attribute__((ext_vector_type(8))) __bf16;

__device__ __forceinline__ float fast_exp2(float x) {
  return __builtin_amdgcn_exp2f(x);   // v_exp_f32 (native exp2 on gfx950)
}

__device__ __forceinline__ int cvt_pk_bf16(float lo, float hi_) {
  int r;
  asm("v_cvt_pk_bf16_f32 %0, %1, %2" : "=v"(r) : "v"(lo), "v"(hi_));
  return r;   // low 16 = bf16(lo), high 16 = bf16(hi_)
}

__device__ __forceinline__ f32x2 max2(f32x2 a, f32x2 b) {
  return __builtin_elementwise_max(a, b);   // v_pk_max_f32
}

__device__ __forceinline__ void gload_lds16(const void* g, void* l) {
  __builtin_amdgcn_global_load_lds(
      (__attribute__((address_space(1))) void*)(void*)(g),
      (__attribute__((address_space(3))) void*)(l), 16, 0, 0);
}

// ---------------- fp32 -> bf16 converts ----------------
__global__ __launch_bounds__(256)
void cvt_f32_bf16(const float* __restrict__ s, __bf16* __restrict__ d, int n4) {
  int i = blockIdx.x * 256 + threadIdx.x;
  if (i >= n4) return;
  float4 v = ((const float4*)s)[i];
  bf16x4 o;
  o[0] = (__bf16)v.x; o[1] = (__bf16)v.y; o[2] = (__bf16)v.z; o[3] = (__bf16)v.w;
  *(bf16x4*)(d + (size_t)i * 4) = o;
}

// 4 weights in one launch; Wq scaled by SCQ and Wq/Wk/Wv written into the
// contiguous [3072][1024] concat buffer (order q,k,v); Wp separate.
__global__ __launch_bounds__(256)
void cvt_w4(const float* __restrict__ Wq, const float* __restrict__ Wk,
            const float* __restrict__ Wv, const float* __restrict__ Wp,
            __bf16* __restrict__ wqkv, __bf16* __restrict__ wpb) {
  int which = blockIdx.y;
  const float* s = which == 0 ? Wq : which == 1 ? Wk : which == 2 ? Wv : Wp;
  __bf16* d = which == 3 ? wpb : wqkv + (size_t)which * CC * CC;
  float sc = which == 0 ? SCQ : 1.f;
  int i = blockIdx.x * 256 + threadIdx.x;   // grid.x = (CC*CC/4)/256 = 1024
  float4 v = ((const float4*)s)[i];
  bf16x4 o;
  o[0] = (__bf16)(v.x * sc); o[1] = (__bf16)(v.y * sc);
  o[2] = (__bf16)(v.z * sc); o[3] = (__bf16)(v.w * sc);
  *(bf16x4*)(d + (size_t)i * 4) = o;
}

#define WAITV4 asm volatile("s_waitcnt vmcnt(4)" ::: "memory")
#define WAITV0 asm volatile("s_waitcnt vmcnt(0)" ::: "memory")
#define BARR   __builtin_amdgcn_s_barrier()
#define SB0    __builtin_amdgcn_sched_barrier(0)

// ==== QKV GEMM v13: triple buffer, prefetch distance 2 (best measured) ======
// C[8192,3072] = A[8192,1024] x Wqkv[3072,1024]^T + bias.
// Session-final configuration (r13 = 168.87us, reproduced r15 = 169.55us).
// r16 falsified the LDS-volume theory: B-direct-from-global halved LDS
// traffic but regressed 78->124us — LDS staging is a latency-decoupling
// buffer, not just bandwidth. This structure's ledger: prologue stages k0,k1
// (8 outstanding); per iter: WAITV4 (drain oldest 4 = stage(t); stage(t+1)
// stays in flight); BARR; issue stage(t+2) into buf[(t+2)%3]; compute
// buf[t%3]. vmcnt never 0 in steady state. LDS 48KB. Slot-swizzle staging/
// read: conflicts = 0. proj 0/1 (Q,K): bf16 head-split store; proj 2 (V):
// 2x 64-col LDS transpose chunks -> Vt[bh][d][t] (lt aliases buffers).
__global__ __launch_bounds__(256, 2)
void gemm_qkv(const __bf16* __restrict__ A, const __bf16* __restrict__ Bm,
              const float* __restrict__ b0, const float* __restrict__ b1,
              const float* __restrict__ b2, __bf16* __restrict__ out,
              __bf16* __restrict__ vt) {
  __shared__ __bf16 U[24576];        // 48KB: A bufs 0..2 @ b*8192, B @ 24576+b*8192
  char* Ub = (char*)U;
  const int tid = threadIdx.x;
  const int wid = tid >> 6, lane = tid & 63;
  const int g = lane >> 4, lq = lane & 15;
  // XCD-chunk swizzle: 1536 blocks = 8 XCDs x 192 contiguous logicals
  const int bx0 = blockIdx.x;
  const int bx = (bx0 & 7) * 192 + (bx0 >> 3);
  const int bm = bx / 24, bn = bx % 24;
  const int brow = bm << 7, bcol = bn << 7;
  const int wr = (wid >> 1) << 6, wc = (wid & 1) << 6;

  // staging: thread handles chunks c0=tid, c1=tid+256 per array (16B each).
  // chunk c -> LDS row c>>2, slot c&3 (linear dest); global source column is
  // inverse-swizzled so read-side slot=(g+(row>>1))&3 recovers K-chunk g.
  const int c0 = tid, c1 = tid + 256;
  const int r0 = c0 >> 2, s0_ = (((c0 & 3) - (r0 >> 1)) & 3) << 4;
  const int r1 = c1 >> 2, s1_ = (((c1 & 3) - (r1 >> 1)) & 3) << 4;
  const char* Ag = (const char*)A;
  const char* Bg = (const char*)Bm;

#define STAGEQ(ko, buf)                                                       \
  {                                                                           \
    gload_lds16(Ag + (size_t)(brow + r0) * 2048 + (ko) + s0_,                 \
                Ub + (buf) * 8192 + c0 * 16);                                 \
    gload_lds16(Ag + (size_t)(brow + r1) * 2048 + (ko) + s1_,                 \
                Ub + (buf) * 8192 + c1 * 16);                                 \
    gload_lds16(Bg + (size_t)(bcol + r0) * 2048 + (ko) + s0_,                 \
                Ub + 24576 + (buf) * 8192 + c0 * 16);                         \
    gload_lds16(Bg + (size_t)(bcol + r1) * 2048 + (ko) + s1_,                 \
                Ub + 24576 + (buf) * 8192 + c1 * 16);                         \
  }

  f32x4 acc[4][4] = {};

  STAGEQ(0, 0); STAGEQ(64, 1);       // prologue: k0,k1 (8 outstanding)
  int cur = 0;
#pragma unroll 1
  for (int t = 0; t < 32; ++t) {
    if (t + 1 < 32) { WAITV4; } else { WAITV0; }  // stage(t) landed
    BARR; SB0;                       // visible to all; buf[(t+2)%3] free
    if (t + 2 < 32) {
      int nb = cur + 2; if (nb >= 3) nb -= 3;
      STAGEQ((t + 2) << 6, nb);
    }
    const char* Ac = Ub + cur * 8192;
    const char* Bc = Ub + 24576 + cur * 8192;
    bf16x8 av[4], bv[4];
#pragma unroll
    for (int m = 0; m < 4; ++m) {
      int row = wr + m * 16 + lq;
      int sl = (g + (row >> 1)) & 3;
      av[m] = *(const bf16x8*)(Ac + row * 64 + sl * 16);
    }
#pragma unroll
    for (int n = 0; n < 4; ++n) {
      int row = wc + n * 16 + lq;
      int sl = (g + (row >> 1)) & 3;
      bv[n] = *(const bf16x8*)(Bc + row * 64 + sl * 16);
    }
#pragma unroll
    for (int m = 0; m < 4; ++m)
#pragma unroll
      for (int n = 0; n < 4; ++n)
        acc[m][n] = __builtin_amdgcn_mfma_f32_16x16x32_bf16(av[m], bv[n], acc[m][n], 0, 0, 0);
    SB0;
    cur = (cur == 2) ? 0 : cur + 1;
  }
#undef STAGEQ

  const int proj = bn >> 3;   // uniform per block (8 x 128 = 1024 cols / proj)
  if (proj < 2) {
    // epilogue: bias + bf16 head-split store [proj][B,H,T,HD]
    const float* bias = proj == 0 ? b0 : b1;
    const float bsc = proj == 0 ? SCQ : 1.f;
#pragma unroll
    for (int n = 0; n < 4; ++n) {
      int col = bcol + wc + n * 16 + lq;
      int cw = col & (CC - 1);
      float bb = bias[cw] * bsc;
      int h_ = cw >> 6, d_ = cw & (HD - 1);
#pragma unroll
      for (int m = 0; m < 4; ++m) {
        int row0 = brow + wr + m * 16 + g * 4;
#pragma unroll
        for (int i = 0; i < 4; ++i) {
          int row = row0 + i;
          int b_ = row >> 11, t_ = row & (TT - 1);
          out[((size_t)proj << 23) +
              ((((size_t)b_ * HH + h_) * TT + t_) << 6) + d_] =
              (__bf16)(acc[m][n][i] + bb);
        }
      }
    }
  } else {
    // V: transpose 128x128 tile through lt (2 chunks of 64 cols = 1 head
    // each) -> Vt[bh][d][t] coalesced. lt ALIASES buffers: barrier first.
    __syncthreads();                             // all K-loop LDS reads done
    __bf16* lt = U;                              // [64 cols][130 rows]
    const int cv0 = (bn & 7) << 7;               // col offset within V region
    const int b_ = brow >> 11, t0 = brow & (TT - 1);
    const int hbase = (bn & 7) << 1;
    const int rd_d = tid >> 2, rd_tb = (tid & 3) << 5;   // 64 d x 128 t
#pragma unroll
    for (int cc = 0; cc < 2; ++cc) {
      if ((wid & 1) == cc) {                     // 2 writer waves per chunk
#pragma unroll
        for (int n = 0; n < 4; ++n) {
          int c = (n << 4) + lq;                 // 0..63 within chunk
          float bb = b2[cv0 + (cc << 6) + c];
#pragma unroll
          for (int m = 0; m < 4; ++m) {
            int r = wr + (m << 4) + (g << 2);    // 0..127 over both writers
            bf16x4 pk;
#pragma unroll
            for (int i = 0; i < 4; ++i)
              pk[i] = (__bf16)(acc[m][n][i] + bb);
            *(bf16x4*)(lt + c * 130 + r) = pk;
          }
        }
      }
      __syncthreads();
      // readers: all 256 threads; d = tid>>2, 32 t-elems each
      __bf16* dst = vt + (((size_t)((b_ * HH + hbase + cc) * HD + rd_d)) << 11)
                       + t0 + rd_tb;
      const __bf16* srcl = lt + rd_d * 130 + rd_tb;
#pragma unroll
      for (int j = 0; j < 4; ++j)
        *(bf16x8*)(dst + j * 8) = *(const bf16x8*)(srcl + j * 8);
      __syncthreads();
    }
  }
}

// ==== proj GEMM v13: same triple-buffered pipeline, fp32 out ================
__global__ __launch_bounds__(256, 2)
void gemm_proj(const __bf16* __restrict__ A, const __bf16* __restrict__ Bm,
               const float* __restrict__ bias, float* __restrict__ out) {
  __shared__ __bf16 U[24576];        // 48KB: A bufs @ b*8192, B @ 24576+b*8192
  char* Ub = (char*)U;
  const int tid = threadIdx.x;
  const int wid = tid >> 6, lane = tid & 63;
  const int g = lane >> 4, lq = lane & 15;
  // XCD-chunk swizzle: 512 blocks = 8 XCDs x 64 contiguous logicals
  const int bx0 = blockIdx.x;
  const int bx = (bx0 & 7) * 64 + (bx0 >> 3);
  const int brow = (bx >> 3) << 7;         // 64 bm
  const int bcol = (bx & 7) << 7;          // 8 bn
  const int wr = (wid >> 1) << 6, wc = (wid & 1) << 6;

  const int c0 = tid, c1 = tid + 256;
  const int r0 = c0 >> 2, s0_ = (((c0 & 3) - (r0 >> 1)) & 3) << 4;
  const int r1 = c1 >> 2, s1_ = (((c1 & 3) - (r1 >> 1)) & 3) << 4;
  const char* Ag = (const char*)A;
  const char* Bg = (const char*)Bm;

#define STAGEP(ko, buf)                                                       \
  {                                                                           \
    gload_lds16(Ag + (size_t)(brow + r0) * 2048 + (ko) + s0_,                 \
                Ub + (buf) * 8192 + c0 * 16);                                 \
    gload_lds16(Ag + (size_t)(brow + r1) * 2048 + (ko) + s1_,                 \
                Ub + (buf) * 8192 + c1 * 16);                                 \
    gload_lds16(Bg + (size_t)(bcol + r0) * 2048 + (ko) + s0_,                 \
                Ub + 24576 + (buf) * 8192 + c0 * 16);                         \
    gload_lds16(Bg + (size_t)(bcol + r1) * 2048 + (ko) + s1_,                 \
                Ub + 24576 + (buf) * 8192 + c1 * 16);                         \
  }

  f32x4 acc[4][4] = {};

  STAGEP(0, 0); STAGEP(64, 1);
  int cur = 0;
#pragma unroll 1
  for (int t = 0; t < 32; ++t) {
    if (t + 1 < 32) { WAITV4; } else { WAITV0; }
    BARR; SB0;
    if (t + 2 < 32) {
      int nb = cur + 2; if (nb >= 3) nb -= 3;
      STAGEP((t + 2) << 6, nb);
    }
    const char* Ac = Ub + cur * 8192;
    const char* Bc = Ub + 24576 + cur * 8192;
    bf16x8 av[4], bv[4];
#pragma unroll
    for (int m = 0; m < 4; ++m) {
      int row = wr + m * 16 + lq;
      int sl = (g + (row >> 1)) & 3;
      av[m] = *(const bf16x8*)(Ac + row * 64 + sl * 16);
    }
#pragma unroll
    for (int n = 0; n < 4; ++n) {
      int row = wc + n * 16 + lq;
      int sl = (g + (row >> 1)) & 3;
      bv[n] = *(const bf16x8*)(Bc + row * 64 + sl * 16);
    }
#pragma unroll
    for (int m = 0; m < 4; ++m)
#pragma unroll
      for (int n = 0; n < 4; ++n)
        acc[m][n] = __builtin_amdgcn_mfma_f32_16x16x32_bf16(av[m], bv[n], acc[m][n], 0, 0, 0);
    SB0;
    cur = (cur == 2) ? 0 : cur + 1;
  }
#undef STAGEP

#pragma unroll
  for (int m = 0; m < 4; ++m) {
#pragma unroll
    for (int n = 0; n < 4; ++n) {
      int col = bcol + wc + n * 16 + lq;
      float bb = bias[col];
      int row0 = brow + wr + m * 16 + g * 4;
#pragma unroll
      for (int i = 0; i < 4; ++i)
        out[(size_t)(row0 + i) * CC + col] = acc[m][n][i] + bb;
    }
  }
}

// ---------------- Flash attention v6 (causal + padding mask) ----------------
// grid 1024 = 16 q-tiles x 64 bh, 256 threads = 4 waves x 32 q-rows (QBLK=128).
// 32x32x16 MFMA, swapped QK^T, split-half S, in-register softmax.
// Full-grid residency: double-buffered K/V (32.8KB LDS) + launch_bounds(256,4)
// -> 4 blocks/CU -> all 1024 blocks co-resident. Heavy-first Latin-square qi
// map balances per-CU work. One barrier per tile, counted staging.
// C/D layout (m74/m101): col = lane&31, row = (r&3) + 8*(r>>2) + 4*(lane>>5).
__global__ __launch_bounds__(256, 4)
void attn_fwd(const __bf16* __restrict__ Q, const __bf16* __restrict__ K,
              const __bf16* __restrict__ Vt, const int* __restrict__ pm,
              __bf16* __restrict__ Y) {
  __shared__ __bf16 Ks[2][64 * 64];   // 16 KiB
  __shared__ __bf16 Vs[2][64 * 64];   // 16 KiB
  __shared__ int flg;
  const int tid = threadIdx.x, wid = tid >> 6, lane = tid & 63;
  const int l31 = lane & 31, hi = lane >> 5;
  const int bx = blockIdx.x;
  const int bh = bx & 63, jj = bx >> 6;          // jj 0..15
  const int qi = 15 - (4 * (jj >> 2) + ((jj + (jj >> 2)) & 3));
  const int b_ = bh >> 4, h_ = bh & 15;
  const __bf16* Qb = Q + (size_t)bh * TT * HD;
  const __bf16* Kb = K + (size_t)bh * TT * HD;
  const __bf16* Vb = Vt + (size_t)bh * HD * TT;
  const int* pmb = pm + b_ * TT;

  const int so = tid * 16;                 // 16B chunk, 0..4080
  const int srow = tid >> 3;               // 0..31
  const int scol = (so & 127) ^ ((srow & 7) << 4);   // inverse-swizzled src col

  const int q0 = qi << 7;
  const int qw = q0 + wid * 32;            // this wave's 32 q-rows
  const int ntiles = 2 * qi + 2;           // >= 2 always
  const int sw0 = (l31 & 7) << 4;

  // Q fragments: lane holds Q[qw+l31][16s + 8hi .. +7], s=0..3
  bf16x8 qf[4];
#pragma unroll
  for (int s = 0; s < 4; ++s)
    qf[s] = *(const bf16x8*)(Qb + (size_t)(qw + l31) * HD + s * 16 + hi * 8);
  SB0;   // pin qf loads above the staging issues (vmcnt accounting)

  // padding-mask block check: 256 threads x 2 int4 cover the 2048-int pm row
  int4 pa4 = ((const int4*)pmb)[tid];
  int4 pb4 = ((const int4*)pmb)[tid + 256];
  bool okp = pa4.x && pa4.y && pa4.z && pa4.w &&
             pb4.x && pb4.y && pb4.z && pb4.w;
  if (tid == 0) flg = 1;
  __syncthreads();
  if (!okp) flg = 0;                       // benign race (all writers store 0)

  // prologue: stage tile 0 into buf 0 (4 gloads: 2 K + 2 V)
  {
    char* kd = (char*)&Ks[0][0] + so;
    char* vd = (char*)&Vs[0][0] + so;
#pragma unroll
    for (int j = 0; j < 2; ++j) {
      gload_lds16((const char*)Kb + (size_t)(srow + 32 * j) * 128 + scol,
                  kd + j * 4096);
      gload_lds16((const char*)Vb + (size_t)(srow + 32 * j) * (TT * 2) + scol,
                  vd + j * 4096);
    }
  }
  __syncthreads();                         // tile 0 staged everywhere; flg final
  const bool allones = (flg != 0);

  f32x16 o0 = {}, o1 = {};                 // O[q=crow(r,hi)][d = l31 | 32+l31]
  f32x16 vzero = {};                       // persistent zero C-operand
  float lsum = 0.f;                        // partial row-sum (this lane-half)
  float m = -INFINITY;                     // running max for q = qw+l31

  int cur = 0;
#pragma unroll 1
  for (int t = 0; t < ntiles; ++t) {
    const int kv0 = t << 6;
    // ---- own stage(t) done (issued a full compute phase ago -> cheap) ----
    WAITV0;
    __builtin_amdgcn_s_barrier(); SB0;  // tile t staged AND t-1 reads done
    // ---- issue stage(t+1) into buf[cur^1] (tile t-1's slot, now free) ----
    if (t + 1 < ntiles) {
      char* kd = (char*)&Ks[0][0] + (cur ^ 1) * 8192 + so;
      char* vd = (char*)&Vs[0][0] + (cur ^ 1) * 8192 + so;
      const size_t nk = (size_t)(kv0 + 64);
#pragma unroll
      for (int j = 0; j < 2; ++j) {
        gload_lds16((const char*)Kb + (nk + srow + 32 * j) * 128 + scol,
                    kd + j * 4096);
        gload_lds16((const char*)Vb + (size_t)(srow + 32 * j) * (TT * 2) +
                        nk * 2 + scol,
                    vd + j * 4096);
      }
    }

    unsigned long long bits = ~0ull;
    if (__builtin_expect(!allones, 0))     // rare slow path
      bits = __ballot(pmb[kv0 + lane] != 0);

    if (kv0 <= qw + 31) {                  // wave-uniform participation
      const char* VsC = (const char*)&Vs[0][0] + cur * 8192;

#pragma unroll
      for (int h = 0; h < 2; ++h) {
        const int kvh = kv0 + 32 * h;
        if (kvh <= qw + 31) {              // wave-uniform per-half gate
          // ---- QK^T (swapped): S[kvh+crow][q=l31] ----
          const char* KsC =
              (const char*)&Ks[0][0] + cur * 8192 + (32 * h + l31) * 128;
          f32x16 S;
          __builtin_amdgcn_s_setprio(1);
          {
            bf16x8 k0 = *(const bf16x8*)(KsC + ((16 * hi) ^ sw0));
            S = __builtin_amdgcn_mfma_f32_32x32x16_bf16(k0, qf[0], vzero, 0, 0, 0);
          }
#pragma unroll
          for (int s = 1; s < 4; ++s) {
            bf16x8 kf = *(const bf16x8*)(KsC + ((32 * s + 16 * hi) ^ sw0));
            S = __builtin_amdgcn_mfma_f32_32x32x16_bf16(kf, qf[s], S, 0, 0, 0);
          }
          __builtin_amdgcn_s_setprio(0);

          // ---- masks ----
          if (__builtin_expect(bits != ~0ull, 0)) {   // padding (rare)
#pragma unroll
            for (int r = 0; r < 16; ++r) {
              const int c = (r & 3) + 8 * (r >> 2);
              if (!((bits >> (32 * h + c + 4 * hi)) & 1ull)) S[r] = -INFINITY;
            }
          }
          if (kvh + 31 > qw) {             // causal diag (wave-uniform)
            const int thr = qw + l31 - kvh - 4 * hi;
#pragma unroll
            for (int r = 0; r < 16; ++r) {
              const int c = (r & 3) + 8 * (r >> 2);
              S[r] = (c <= thr) ? S[r] : -INFINITY;
            }
          }

          // ---- row max via packed-f32 tree + defer-rescale check ----
          f32x2 x0 = {S[0], S[1]},  x1 = {S[2], S[3]};
          f32x2 x2 = {S[4], S[5]},  x3 = {S[6], S[7]};
          f32x2 x4 = {S[8], S[9]},  x5 = {S[10], S[11]};
          f32x2 x6 = {S[12], S[13]}, x7 = {S[14], S[15]};
          x0 = max2(x0, x4); x1 = max2(x1, x5);
          x2 = max2(x2, x6); x3 = max2(x3, x7);
          x0 = max2(x0, x2); x1 = max2(x1, x3);
          x0 = max2(x0, x1);
          float pmax = fmaxf(x0[0], x0[1]);
          if (!__all(pmax <= m + 8.f)) {
            float nm = fmaxf(pmax, __shfl_xor(pmax, 32));  // full row max
            float mn = fmaxf(m, nm);
            float c = fast_exp2(m - mn);
            m = mn;
            lsum *= c;
#pragma unroll
            for (int r = 0; r < 16; ++r) {
              float cr = __shfl(c, (r & 3) + 8 * (r >> 2) + 4 * hi);
              o0[r] *= cr;
              o1[r] *= cr;
            }
          }

          // ---- P = exp2(S - m) (packed sub, trans exp) ----
          const f32x2 mm = {m, m};
#pragma unroll
          for (int r = 0; r < 16; r += 2) {
            f32x2 u = {S[r], S[r + 1]};
            u -= mm;                      // v_pk_add_f32
            S[r] = fast_exp2(u[0]);
            S[r + 1] = fast_exp2(u[1]);
          }
          // ---- in-lane row-sum via packed-f32 tree ----
          {
            f32x2 u0 = {S[0], S[1]},  u1 = {S[2], S[3]};
            f32x2 u2 = {S[4], S[5]},  u3 = {S[6], S[7]};
            f32x2 u4 = {S[8], S[9]},  u5 = {S[10], S[11]};
            f32x2 u6 = {S[12], S[13]}, u7 = {S[14], S[15]};
            u0 += u4; u1 += u5; u2 += u6; u3 += u7;
            u0 += u2; u1 += u3;
            u0 += u1;
            lsum += u0[0] + u0[1];
          }

          // ---- PV: build A-fragments (validated select+shfl_xor exchange) ----
          __builtin_amdgcn_s_setprio(1);
#pragma unroll
          for (int s = 0; s < 2; ++s) {
            int A0 = cvt_pk_bf16(S[8 * s + 0], S[8 * s + 1]);
            int A1 = cvt_pk_bf16(S[8 * s + 2], S[8 * s + 3]);
            int B0 = cvt_pk_bf16(S[8 * s + 4], S[8 * s + 5]);
            int B1 = cvt_pk_bf16(S[8 * s + 6], S[8 * s + 7]);
            // exchange across lane+-32: lo lanes need A-pairs of BOTH halves,
            // hi lanes need B-pairs of BOTH halves.
            int s0 = hi ? A0 : B0, s1 = hi ? A1 : B1;
            int e0 = __shfl_xor(s0, 32), e1 = __shfl_xor(s1, 32);
            i32x4 wv;
            wv[0] = hi ? e0 : A0;
            wv[1] = hi ? e1 : A1;
            wv[2] = hi ? B0 : e0;
            wv[3] = hi ? B1 : e1;
            bf16x8 pa = __builtin_bit_cast(bf16x8, wv);
            const int co = 64 * h + 32 * s + 16 * hi;   // kv byte offset
            bf16x8 v0 = *(const bf16x8*)(VsC + l31 * 128 + (co ^ sw0));
            bf16x8 v1 = *(const bf16x8*)(VsC + (32 + l31) * 128 + (co ^ sw0));
            o0 = __builtin_amdgcn_mfma_f32_32x32x16_bf16(pa, v0, o0, 0, 0, 0);
            o1 = __builtin_amdgcn_mfma_f32_32x32x16_bf16(pa, v1, o1, 0, 0, 0);
          }
          __builtin_amdgcn_s_setprio(0);
        }
      }
    }
    SB0;   // pin this tile's LDS reads above next iteration's barrier
    cur ^= 1;
  }

  // epilogue: combine lane-halves' row-sums, normalize + store
  float linv = 1.f / (lsum + __shfl_xor(lsum, 32));
#pragma unroll
  for (int r = 0; r < 16; ++r) {
    const int crow = (r & 3) + 8 * (r >> 2) + 4 * hi;
    float ir = __shfl(linv, crow);
    const int qrow = qw + crow;
    __bf16* yp = Y + ((size_t)(b_ * TT + qrow)) * CC + h_ * HD + l31;
    yp[0]  = (__bf16)(o0[r] * ir);
    yp[32] = (__bf16)(o1[r] * ir);
  }
}

// ---------------- launch ----------------
extern "C" void kernel_launch(void* const* d_in, const int* in_sizes, int n_in,
                              void* d_out, int out_size, void* d_ws, size_t ws_size,
                              hipStream_t stream) {
  (void)in_sizes; (void)n_in; (void)out_size; (void)ws_size;
  const float* x  = (const float*)d_in[0];
  const float* Wk = (const float*)d_in[1];
  const float* bk = (const float*)d_in[2];
  const float* Wq = (const float*)d_in[3];
  const float* bq = (const float*)d_in[4];
  const float* Wv = (const float*)d_in[5];
  const float* bv = (const float*)d_in[6];
  const float* Wp = (const float*)d_in[7];
  const float* bp = (const float*)d_in[8];
  const int* pmask = (const int*)d_in[9];

  char* ws = (char*)d_ws;
  const size_t MB = 1024 * 1024;
  __bf16* xb   = (__bf16*)(ws);            // 16MB; reused as attn-out y
  __bf16* wqkv = (__bf16*)(ws + 16 * MB);  // 6MB  [3072][1024] (q,k,v concat)
  __bf16* wpb  = (__bf16*)(ws + 22 * MB);  // 2MB
  __bf16* qb   = (__bf16*)(ws + 24 * MB);  // 16MB [B,H,T,HD]
  __bf16* kb   = qb + ((size_t)1 << 23);   // 16MB @40MB
  __bf16* vtb  = (__bf16*)(ws + 56 * MB);  // 16MB [B,H,HD,T] (written by gemm_qkv)
  __bf16* yb   = xb;                       // attn out overwrites x

  int n4 = (MM * CC) / 4;                  // 2097152
  cvt_f32_bf16<<<(n4 + 255) / 256, 256, 0, stream>>>(x, xb, n4);
  cvt_w4<<<dim3((CC * CC / 4) / 256, 4), 256, 0, stream>>>(
      Wq, Wk, Wv, Wp, wqkv, wpb);

  // fused QKV projection + V-transpose epilogue (128x128 tiles, grid 1536)
  gemm_qkv<<<(MM / 128) * (3 * CC / 128), 256, 0, stream>>>(
      xb, wqkv, bq, bk, bv, qb, vtb);

  attn_fwd<<<NQT2 * BB * HH, 256, 0, stream>>>(qb, kb, vtb, pmask, yb);

  gemm_proj<<<(MM / 128) * (CC / 128), 256, 0, stream>>>(
      yb, wpb, bp, (float*)d_out);
}